// Round 8
// baseline (620.621 us; speedup 1.0000x reference)
//
#include <hip/hip_runtime.h>
#include <hip/hip_cooperative_groups.h>
#include <math.h>

namespace cg = cooperative_groups;

// Caffe-style RPN proposal layer on gfx950 — single cooperative kernel.
// scores (1,64,64,18) f32 + deltas (1,64,64,36) f32 -> (300,4) f32.
// Phases (5 grid syncs): A decode+hist -> B flush -> C threshold + D compact
// -> E rank+scatter -> F IoU bitmask -> G greedy scan (block 0) + output.

#define NPROP   36864
#define TOPN    6000
#define POSTN   300
#define NWORDS  94          // ceil(6000/64)
#define NROUND  47          // ceil(6000/128)
#define MAXSEL  8192
#define NB      16384       // 14-bit histogram buckets
#define NTILE   4465        // 94*95/2 upper-tri tiles
#define NEGINF_PAT 0x007FFFFFu   // sortable pattern of -inf score

typedef unsigned long long u64;

// classic 9 anchors for base=16, ratios {0.5,1,2}, scales {8,16,32}
__constant__ float ANCH[9][4] = {
    {-84.f,  -40.f,  99.f,  55.f},
    {-176.f, -88.f,  191.f, 103.f},
    {-360.f, -184.f, 375.f, 199.f},
    {-56.f,  -56.f,  71.f,  71.f},
    {-120.f, -120.f, 135.f, 135.f},
    {-248.f, -248.f, 263.f, 263.f},
    {-36.f,  -80.f,  51.f,  95.f},
    {-80.f,  -168.f, 95.f,  183.f},
    {-168.f, -344.f, 183.f, 359.f},
};

// decode box for anchor-index i (match unfused numpy rounding: no FMA)
__device__ __forceinline__ float4 decode_box(const float* __restrict__ deltas, int i,
                                             bool* valid_out) {
    int a   = i % 9;
    int pos = i / 9;
    int wx = pos & 63, hy = pos >> 6;
    float sx = (float)(wx * 16), sy = (float)(hy * 16);
    float ax1 = ANCH[a][0] + sx, ay1 = ANCH[a][1] + sy;
    float ax2 = ANCH[a][2] + sx, ay2 = ANCH[a][3] + sy;
    float aw  = ax2 - ax1 + 1.0f;
    float ah  = ay2 - ay1 + 1.0f;
    float acx = ax1 + 0.5f * aw;
    float acy = ay1 + 0.5f * ah;
    float4 d4 = ((const float4*)deltas)[i];   // (pos*36+a*4) floats == i*4 floats
    float pcx = __fadd_rn(__fmul_rn(d4.x, aw), acx);
    float pcy = __fadd_rn(__fmul_rn(d4.y, ah), acy);
    float pw  = __fmul_rn(expf(d4.z), aw);
    float ph  = __fmul_rn(expf(d4.w), ah);
    float hx  = __fmul_rn(0.5f, pw);
    float hv  = __fmul_rn(0.5f, ph);
    float x1 = fminf(fmaxf(__fsub_rn(pcx, hx), 0.0f), 1023.0f);
    float y1 = fminf(fmaxf(__fsub_rn(pcy, hv), 0.0f), 1023.0f);
    float x2 = fminf(fmaxf(__fadd_rn(pcx, hx), 0.0f), 1023.0f);
    float y2 = fminf(fmaxf(__fadd_rn(pcy, hv), 0.0f), 1023.0f);
    float bw = __fadd_rn(__fsub_rn(x2, x1), 1.0f);
    float bh = __fadd_rn(__fsub_rn(y2, y1), 1.0f);
    *valid_out = (bw >= 16.0f) && (bh >= 16.0f);
    return make_float4(x1, y1, x2, y2);
}

__device__ __forceinline__ float box_area(float4 b) {
    return __fmul_rn(__fadd_rn(__fsub_rn(b.z, b.x), 1.0f),
                     __fadd_rn(__fsub_rn(b.w, b.y), 1.0f));
}

__device__ __forceinline__ float iou_fn(float4 a, float aa, float4 b, float ab) {
    float xx1 = fmaxf(a.x, b.x);
    float yy1 = fmaxf(a.y, b.y);
    float xx2 = fminf(a.z, b.z);
    float yy2 = fminf(a.w, b.w);
    float w = fmaxf(__fadd_rn(__fsub_rn(xx2, xx1), 1.0f), 0.0f);
    float h = fmaxf(__fadd_rn(__fsub_rn(yy2, yy1), 1.0f), 0.0f);
    float inter = __fmul_rn(w, h);
    return inter / __fsub_rn(__fadd_rn(aa, ab), inter);   // IEEE-exact
}

__global__ __launch_bounds__(1024, 4) void fused_proposal(
        const float* __restrict__ scores,
        const float* __restrict__ deltas,
        unsigned* __restrict__ ghist,
        u64* __restrict__ sel,
        unsigned* __restrict__ nselg,
        float4* __restrict__ topb,
        float* __restrict__ areas,
        unsigned* __restrict__ topu,
        u64* __restrict__ mask,
        float* __restrict__ out) {
    cg::grid_group grid = cg::this_grid();

    __shared__ char big[65536];            // union region, phase-dependent
    __shared__ unsigned thr_sh, bcnt, bbase;
    // scan statics (block 0, phase G)
    __shared__ unsigned rem32[NWORDS * 2];
    __shared__ u64 Fsh[2][2];
    __shared__ short kept_rows[2][128];
    __shared__ short kept_list[POSTN];
    __shared__ int nk_sh[2];
    __shared__ int cnt_sh, stop_sh;

    const int t = threadIdx.x, b = blockIdx.x;
    const int lane = t & 63, wave = t >> 6;
    const int g = b * 1024 + t;

    // ================= phase A: zero ghist/nselg + decode + LDS hist ========
    unsigned* histL = (unsigned*)big;
    #pragma unroll
    for (int r = 0; r < NB / 1024; ++r) histL[t + r * 1024] = 0;
    if (g < NB) ghist[g] = 0;
    if (g == NB) *nselg = 0;
    __syncthreads();

    unsigned myu = 0;                      // register-carried score key
    if (b < 36) {                          // 36 blocks * 1024 == NPROP exactly
        bool valid;
        (void)decode_box(deltas, g, &valid);
        int a = g % 9, pos = g / 9;
        float fg = scores[(size_t)pos * 18 + 9 + a];
        float sc = valid ? fg : -__builtin_huge_valf();
        unsigned u = __float_as_uint(sc);
        myu = (u & 0x80000000u) ? ~u : (u | 0x80000000u);   // bigger = better
        atomicAdd(&histL[myu >> 18], 1u);
    }
    __syncthreads();
    __threadfence();
    grid.sync();   // #1: zeros visible everywhere

    // ================= phase B: flush block-private hist ====================
    if (b < 36) {
        #pragma unroll
        for (int r = 0; r < NB / 1024; ++r) {
            unsigned v = histL[t + r * 1024];
            if (v) atomicAdd(&ghist[t + r * 1024], v);
        }
    }
    __threadfence();
    grid.sync();   // #2: ghist complete

    // ================= phase C: threshold (every block, redundantly) ========
    unsigned* strip = (unsigned*)big;      // histL dead
    {
        const uint4* g4 = (const uint4*)ghist;
        uint4 qa = g4[t * 4], qb = g4[t * 4 + 1], qc = g4[t * 4 + 2], qd = g4[t * 4 + 3];
        strip[t] = qa.x + qa.y + qa.z + qa.w + qb.x + qb.y + qb.z + qb.w
                 + qc.x + qc.y + qc.z + qc.w + qd.x + qd.y + qd.z + qd.w;
    }
    if (t == 0) bcnt = 0;
    __syncthreads();
    if (wave == 0) {
        unsigned gsum = 0;
        #pragma unroll
        for (int k = 0; k < 16; ++k) gsum += strip[lane * 16 + k];
        unsigned suf = gsum;
        #pragma unroll
        for (int off = 1; off < 64; off <<= 1) {
            unsigned x = __shfl_down(suf, off, 64);
            if (lane + off < 64) suf += x;
        }
        u64 bal = __ballot(suf >= TOPN);
        int gsel = 63 - __builtin_clzll(bal);
        unsigned rest = __shfl(suf, (gsel < 63) ? gsel + 1 : 63, 64);
        if (gsel == 63) rest = 0;

        unsigned sv = (lane < 16) ? strip[gsel * 16 + lane] : 0;
        unsigned suf2 = sv;
        #pragma unroll
        for (int off = 1; off < 16; off <<= 1) {
            unsigned x = __shfl_down(suf2, off, 64);
            if (lane + off < 16) suf2 += x;
        }
        u64 bal2 = __ballot((lane < 16) && (rest + suf2 >= TOPN));
        int ssel = 63 - __builtin_clzll(bal2);
        unsigned rest2 = __shfl(suf2, (ssel < 15) ? ssel + 1 : 15, 64);
        if (ssel == 15) rest2 = 0;
        rest2 += rest;
        int S = gsel * 16 + ssel;

        unsigned bv = (lane < 16) ? ghist[S * 16 + lane] : 0;
        unsigned suf3 = bv;
        #pragma unroll
        for (int off = 1; off < 16; off <<= 1) {
            unsigned x = __shfl_down(suf3, off, 64);
            if (lane + off < 16) suf3 += x;
        }
        u64 bal3 = __ballot((lane < 16) && (rest2 + suf3 >= TOPN));
        int bsel = 63 - __builtin_clzll(bal3);
        if (lane == 0) thr_sh = ((unsigned)(S * 16 + bsel)) << 18;
    }
    __syncthreads();
    unsigned thr = thr_sh;                 // count(key >= thr) >= TOPN

    // ================= phase D: two-level ballot compact ====================
    if (b < 36) {
        bool pred = (myu >= thr);
        u64 bal = __ballot(pred);
        unsigned wbase = 0;
        if (lane == 0) wbase = atomicAdd(&bcnt, (unsigned)__popcll(bal));
        wbase = __shfl(wbase, 0, 64);
        __syncthreads();                   // bcnt final
        if (t == 0) bbase = atomicAdd(nselg, bcnt);
        __syncthreads();
        if (pred) {
            unsigned p = bbase + wbase + (unsigned)__popcll(bal & ((1ULL << lane) - 1ULL));
            if (p < MAXSEL)
                sel[p] = ((u64)myu << 32) | (u64)(0xFFFFFFFFu - (unsigned)g);
        }
    }
    __threadfence();
    grid.sync();   // #3: sel + nselg complete

    // ================= phase E: rank (32-way split) + scatter ===============
    {
        int n = (int)*nselg; if (n > MAXSEL) n = MAXSEL;
        u64* tileb = (u64*)big;            // 8 KB
        int* pr    = (int*)(big + 8192);   // 4 KB
        int jslot = t & 31, seg = t >> 5;
        int j = b * 32 + jslot;            // 256 blocks * 32 == MAXSEL
        u64 myk = (j < n) ? sel[j] : 0ULL;
        int rk = 0;
        for (int base = 0; base < n; base += 1024) {
            int m = min(1024, n - base);
            if (t < m) tileb[t] = sel[base + t];
            __syncthreads();
            for (int q = seg; q < m; q += 32) rk += (tileb[q] > myk) ? 1 : 0;
            __syncthreads();
        }
        pr[seg * 32 + jslot] = rk;
        __syncthreads();
        if (t < 32) {
            int jj = b * 32 + t;
            int rtot = 0;
            #pragma unroll
            for (int s2 = 0; s2 < 32; ++s2) rtot += pr[s2 * 32 + t];
            if (jj < n && rtot < TOPN) {
                u64 k = sel[jj];
                unsigned idx = 0xFFFFFFFFu - (unsigned)(k & 0xFFFFFFFFull);
                bool valid;
                float4 bx = decode_box(deltas, (int)idx, &valid);
                topb[rtot]  = bx;
                areas[rtot] = box_area(bx);
                topu[rtot]  = (unsigned)(k >> 32);
            }
        }
    }
    __threadfence();
    grid.sync();   // #4: topb/areas/topu complete

    // ================= phase F: IoU bit matrix, one 64x64 tile per wave =====
    {
        int wv = b * 16 + wave;            // 4096 waves
        for (int L = wv; L < NTILE; L += 4096) {
            int rb = 0, off = 0;
            while (L - off >= 94 - rb) { off += 94 - rb; ++rb; }
            int cb = rb + (L - off);
            int i  = rb * 64 + lane;
            int j0 = cb * 64;
            int jmax = min(64, TOPN - j0);
            bool rowok = (i < TOPN);
            float4 bi = rowok ? topb[i] : make_float4(0.f, 0.f, 0.f, 0.f);
            float  ai = rowok ? areas[i] : 1.f;
            u64 bits = 0ULL;
            #pragma unroll 4
            for (int jj2 = 0; jj2 < jmax; ++jj2) {
                int j = j0 + jj2;
                float4 bj = topb[j];       // broadcast load
                float  aj = areas[j];
                float iou = iou_fn(bi, ai, bj, aj);
                if ((j > i) && (iou > 0.5f)) bits |= (1ULL << jj2);
            }
            if (rowok) mask[(size_t)i * NWORDS + cb] = bits;
        }
    }
    __threadfence();
    grid.sync();   // #5: mask complete

    // ================= phase G: greedy scan (block 0 only) ==================
    if (b != 0) return;

    u64* diagp = (u64*)big;                // 8 KB
    #define DIAG(pp, row, k) diagp[(((((pp) << 7) | (row)) << 2) | (k))]

    if (t < NWORDS * 2) rem32[t] = 0;
    if (t < 512)                           // round-0 tile: rows 0..127, words 0..3
        DIAG(0, t >> 2, t & 3) = mask[(size_t)(t >> 2) * NWORDS + (t & 3)];
    if (wave == 0) {
        u64 f = __ballot(topu[lane] != NEGINF_PAT);
        if (lane == 0) { Fsh[0][0] = f; cnt_sh = 0; stop_sh = 0; nk_sh[0] = 0; nk_sh[1] = 0; }
    } else if (wave == 1) {
        u64 f = __ballot(topu[64 + lane] != NEGINF_PAT);
        if (lane == 0) Fsh[0][1] = f;
    }
    __syncthreads();

    u64 urg0 = 0, urg1 = 0;   // wave0: urgent removed-bits for next round

    for (int r = 0; r < NROUND; ++r) {
        int p = r & 1;
        int i0 = r * 128;
        if (wave == 0) {
            u64 r0w0 = DIAG(p, lane, 0);
            u64 r0w1 = DIAG(p, lane, 1);
            u64 r1w1 = DIAG(p, 64 + lane, 1);
            u64 R0 = ((u64)rem32[4 * r]     | ((u64)rem32[4 * r + 1] << 32)) | urg0;
            u64 R1 = ((u64)rem32[4 * r + 2] | ((u64)rem32[4 * r + 3] << 32)) | urg1;
            int nb = min(128, TOPN - i0);
            u64 v1 = (nb >= 128) ? ~0ULL : ((1ULL << (nb - 64)) - 1ULL);
            u64 a0 = ~R0;
            u64 a1 = ~R1 & v1;
            u64 k0 = 0ULL, k1 = 0ULL;
            while (a0) {
                int ii = __builtin_ctzll(a0);
                u64 bit = 1ULL << ii;
                k0 |= bit;
                u64 s0 = __shfl(r0w0, ii, 64);
                u64 s1 = __shfl(r0w1, ii, 64);
                a0 &= ~(s0 | bit);
                a1 &= ~s1;
            }
            while (a1) {
                int ii = __builtin_ctzll(a1);
                u64 bit = 1ULL << ii;
                k1 |= bit;
                u64 s1 = __shfl(r1w1, ii, 64);
                a1 &= ~(s1 | bit);
            }
            u64 F0 = Fsh[p][0], F1 = Fsh[p][1];
            u64 kf0 = k0 & F0, kf1 = k1 & F1;
            int nk0 = __popcll(k0);
            int c0  = __popcll(kf0);
            int base = cnt_sh;
            u64 ltm = (1ULL << lane) - 1ULL;
            if ((k0 >> lane) & 1)
                kept_rows[p][__popcll(k0 & ltm)] = (short)(i0 + lane);
            if ((k1 >> lane) & 1)
                kept_rows[p][nk0 + __popcll(k1 & ltm)] = (short)(i0 + 64 + lane);
            if ((kf0 >> lane) & 1) {
                int pos = base + __popcll(kf0 & ltm);
                if (pos < POSTN) kept_list[pos] = (short)(i0 + lane);
            }
            if ((kf1 >> lane) & 1) {
                int pos = base + c0 + __popcll(kf1 & ltm);
                if (pos < POSTN) kept_list[pos] = (short)(i0 + 64 + lane);
            }
            u64 a0u = 0ULL, a1u = 0ULL;
            if ((k0 >> lane) & 1) { a0u = DIAG(p, lane, 2);        a1u = DIAG(p, lane, 3); }
            if ((k1 >> lane) & 1) { a0u |= DIAG(p, 64 + lane, 2);  a1u |= DIAG(p, 64 + lane, 3); }
            #pragma unroll
            for (int off = 1; off < 64; off <<= 1) {
                a0u |= __shfl_xor(a0u, off, 64);
                a1u |= __shfl_xor(a1u, off, 64);
            }
            urg0 = a0u; urg1 = a1u;
            if (lane == 0) {
                nk_sh[p] = nk0 + __popcll(k1);
                int cc = base + c0 + __popcll(kf1);
                if (cc > POSTN) cc = POSTN;
                cnt_sh = cc;
                stop_sh = (cc >= POSTN) || (r == NROUND - 1);
            }
        } else if (wave == 15) {
            if (r + 1 < NROUND) {
                int i1 = i0 + 128;
                #pragma unroll
                for (int q = lane; q < 512; q += 64) {
                    int row = i1 + (q >> 2), k = q & 3;
                    int wd = 2 * (r + 1) + k;
                    DIAG(p ^ 1, q >> 2, k) = (row < TOPN && wd < NWORDS)
                        ? mask[(size_t)row * NWORDS + wd] : 0ULL;
                }
                u64 fa = __ballot((i1 + lane < TOPN) && (topu[i1 + lane] != NEGINF_PAT));
                u64 fb = __ballot((i1 + 64 + lane < TOPN) && (topu[i1 + 64 + lane] != NEGINF_PAT));
                if (lane == 0) { Fsh[p ^ 1][0] = fa; Fsh[p ^ 1][1] = fb; }
            }
        } else {
            int nkp = nk_sh[p ^ 1];
            int left = NWORDS - (2 * r + 2);
            if (r > 0 && nkp > 0 && left > 0) {
                int tot = nkp * left;
                for (int q = t - 64; q < tot; q += 896) {
                    int k  = q / left;
                    int wd = 2 * r + 2 + (q - k * left);
                    int row = kept_rows[p ^ 1][k];
                    u64 v = mask[(size_t)row * NWORDS + wd];
                    if (v) {
                        unsigned lo = (unsigned)v, hi = (unsigned)(v >> 32);
                        if (lo) atomicOr(&rem32[2 * wd],     lo);
                        if (hi) atomicOr(&rem32[2 * wd + 1], hi);
                    }
                }
            }
        }
        __syncthreads();
        if (stop_sh) break;
    }

    // fused output: first 300 kept (rank order), /1024, zero-fill rest
    if (t < POSTN) {
        float4 v = make_float4(0.f, 0.f, 0.f, 0.f);
        if (t < cnt_sh) {
            float4 bx = topb[kept_list[t]];
            const float s = 0.0009765625f;   // 1/1024 (exact)
            v = make_float4(bx.x * s, bx.y * s, bx.z * s, bx.w * s);
        }
        ((float4*)out)[t] = v;
    }
    #undef DIAG
}

extern "C" void kernel_launch(void* const* d_in, const int* in_sizes, int n_in,
                              void* d_out, int out_size, void* d_ws, size_t ws_size,
                              hipStream_t stream) {
    const float* scores = (const float*)d_in[0];   // (1,64,64,18)
    const float* deltas = (const float*)d_in[1];   // (1,64,64,36)
    float* out = (float*)d_out;                    // 300*4

    char* w = (char*)d_ws;
    unsigned* ghist = (unsigned*)(w);               //       0 ..   65536
    u64*      sel   = (u64*)(w + 65536);            //   65536 ..  131072
    unsigned* nselg = (unsigned*)(w + 131072);      //  131072 ..  131088
    float4*   topb  = (float4*)(w + 131088);        //  131088 ..  227088
    float*    areas = (float*)(w + 227088);         //  227088 ..  251088
    unsigned* topu  = (unsigned*)(w + 251088);      //  251088 ..  275088
    u64*      mask  = (u64*)(w + 275088);           //  275088 .. 4787088 (4.5 MB)

    void* kargs[] = { (void*)&scores, (void*)&deltas, (void*)&ghist, (void*)&sel,
                      (void*)&nselg, (void*)&topb, (void*)&areas, (void*)&topu,
                      (void*)&mask, (void*)&out };
    hipLaunchCooperativeKernel((const void*)fused_proposal, dim3(256), dim3(1024),
                               kargs, 0, stream);
}

// Round 9
// 175.605 us; speedup vs baseline: 3.5342x; 3.5342x over previous
//
#include <hip/hip_runtime.h>
#include <math.h>

// Caffe-style RPN proposal layer on gfx950.
// scores (1,64,64,18) f32 + deltas (1,64,64,36) f32 -> (300,4) f32.
// Pipeline (5 dispatches):
//   decode (uhigh only)
//   -> select_compact (transposed LDS hist, wave-parallel descent, ballot compact)
//   -> rank_scatter (per-block full rank of 32 candidates + re-decode scatter)
//   -> nms_mask (grid IoU bit matrix) -> nms_scan (latency-hidden greedy, fused out)

#define NPROP   36864
#define TOPN    6000
#define POSTN   300
#define NWORDS  94          // ceil(6000/64)
#define NROUND  47          // ceil(6000/128)
#define MAXSEL  8192
#define NB      16384       // 14-bit histogram buckets
#define NEGINF_PAT 0x007FFFFFu   // sortable pattern of -inf score

typedef unsigned long long u64;

// classic 9 anchors for base=16, ratios {0.5,1,2}, scales {8,16,32}
__constant__ float ANCH[9][4] = {
    {-84.f,  -40.f,  99.f,  55.f},
    {-176.f, -88.f,  191.f, 103.f},
    {-360.f, -184.f, 375.f, 199.f},
    {-56.f,  -56.f,  71.f,  71.f},
    {-120.f, -120.f, 135.f, 135.f},
    {-248.f, -248.f, 263.f, 263.f},
    {-36.f,  -80.f,  51.f,  95.f},
    {-80.f,  -168.f, 95.f,  183.f},
    {-168.f, -344.f, 183.f, 359.f},
};

// decode box for anchor-index i (match unfused numpy rounding: no FMA)
__device__ __forceinline__ float4 decode_box(const float* __restrict__ deltas, int i,
                                             bool* valid_out) {
    int a   = i % 9;
    int pos = i / 9;
    int wx = pos & 63, hy = pos >> 6;
    float sx = (float)(wx * 16), sy = (float)(hy * 16);
    float ax1 = ANCH[a][0] + sx, ay1 = ANCH[a][1] + sy;
    float ax2 = ANCH[a][2] + sx, ay2 = ANCH[a][3] + sy;
    float aw  = ax2 - ax1 + 1.0f;
    float ah  = ay2 - ay1 + 1.0f;
    float acx = ax1 + 0.5f * aw;
    float acy = ay1 + 0.5f * ah;
    float4 d4 = ((const float4*)deltas)[i];   // (pos*36+a*4) floats == i*4 floats
    float pcx = __fadd_rn(__fmul_rn(d4.x, aw), acx);
    float pcy = __fadd_rn(__fmul_rn(d4.y, ah), acy);
    float pw  = __fmul_rn(expf(d4.z), aw);
    float ph  = __fmul_rn(expf(d4.w), ah);
    float hx  = __fmul_rn(0.5f, pw);
    float hv  = __fmul_rn(0.5f, ph);
    float x1 = fminf(fmaxf(__fsub_rn(pcx, hx), 0.0f), 1023.0f);
    float y1 = fminf(fmaxf(__fsub_rn(pcy, hv), 0.0f), 1023.0f);
    float x2 = fminf(fmaxf(__fadd_rn(pcx, hx), 0.0f), 1023.0f);
    float y2 = fminf(fmaxf(__fadd_rn(pcy, hv), 0.0f), 1023.0f);
    float bw = __fadd_rn(__fsub_rn(x2, x1), 1.0f);
    float bh = __fadd_rn(__fsub_rn(y2, y1), 1.0f);
    *valid_out = (bw >= 16.0f) && (bh >= 16.0f);
    return make_float4(x1, y1, x2, y2);
}

__device__ __forceinline__ float box_area(float4 b) {
    return __fmul_rn(__fadd_rn(__fsub_rn(b.z, b.x), 1.0f),
                     __fadd_rn(__fsub_rn(b.w, b.y), 1.0f));
}

// ---------- decode: sortable score word only ----------
__global__ __launch_bounds__(256) void decode_kernel(
        const float* __restrict__ scores,
        const float* __restrict__ deltas,
        unsigned* __restrict__ uhigh) {
    int i = blockIdx.x * 256 + threadIdx.x;   // exactly NPROP threads
    bool valid;
    (void)decode_box(deltas, i, &valid);
    int a = i % 9, pos = i / 9;
    float fg = scores[(size_t)pos * 18 + 9 + a];
    float sc = valid ? fg : -__builtin_huge_valf();
    unsigned u = __float_as_uint(sc);
    u = (u & 0x80000000u) ? ~u : (u | 0x80000000u);   // sortable: bigger = better
    uhigh[i] = u;
}

// ---------- single block: transposed LDS hist + wave-parallel descent + compact ----------
// Histogram storage transposed: bucket i lives at h[(i>>4) + (i&15)*1024], so
// strip sums (thread t owns buckets [16t,16t+16)) read stride-1024 words =
// bank-conflict-free. Threshold descent is a 3-level (64/16/16) shfl suffix
// scan in wave 0 (no serial LDS-latency chain).
__global__ __launch_bounds__(1024) void select_compact(
        const unsigned* __restrict__ uhigh,
        u64* __restrict__ sel,
        unsigned* __restrict__ nsel) {
    __shared__ unsigned h[NB];         // 64 KB, transposed
    __shared__ unsigned strip[1024];
    __shared__ unsigned thr_sh, cnt_sh;
    int t = threadIdx.x, lane = t & 63, wave = t >> 6;
    #pragma unroll
    for (int r = 0; r < NB / 1024; ++r) h[t + r * 1024] = 0;
    if (t == 0) cnt_sh = 0;
    __syncthreads();

    #pragma unroll
    for (int r = 0; r < 36; ++r) {     // NPROP/1024 == 36, coalesced
        unsigned u = uhigh[t + r * 1024];
        unsigned bkt = u >> 18;
        atomicAdd(&h[(bkt >> 4) + (bkt & 15) * 1024], 1u);
    }
    __syncthreads();

    unsigned s = 0;
    #pragma unroll
    for (int k = 0; k < 16; ++k) s += h[t + k * 1024];   // conflict-free
    strip[t] = s;
    __syncthreads();

    if (wave == 0) {
        // level 1: 64 group sums (16 strips each), suffix scan, pick group
        unsigned g = 0;
        #pragma unroll
        for (int k = 0; k < 16; ++k) g += strip[lane * 16 + k];
        unsigned suf = g;
        #pragma unroll
        for (int off = 1; off < 64; off <<= 1) {
            unsigned x = __shfl_down(suf, off, 64);
            if (lane + off < 64) suf += x;
        }
        u64 bal = __ballot(suf >= TOPN);
        int gsel = 63 - __builtin_clzll(bal);
        unsigned rest = __shfl(suf, (gsel < 63) ? gsel + 1 : 63, 64);
        if (gsel == 63) rest = 0;

        // level 2: 16 strips within group gsel
        unsigned sv = (lane < 16) ? strip[gsel * 16 + lane] : 0;
        unsigned suf2 = sv;
        #pragma unroll
        for (int off = 1; off < 16; off <<= 1) {
            unsigned x = __shfl_down(suf2, off, 64);
            if (lane + off < 16) suf2 += x;
        }
        u64 bal2 = __ballot((lane < 16) && (rest + suf2 >= TOPN));
        int ssel = 63 - __builtin_clzll(bal2);
        unsigned rest2 = __shfl(suf2, (ssel < 15) ? ssel + 1 : 15, 64);
        if (ssel == 15) rest2 = 0;
        rest2 += rest;
        int S = gsel * 16 + ssel;      // strip index 0..1023

        // level 3: 16 buckets within strip S; bucket S*16+lane at h[S+lane*1024]
        unsigned bv = (lane < 16) ? h[S + lane * 1024] : 0;
        unsigned suf3 = bv;
        #pragma unroll
        for (int off = 1; off < 16; off <<= 1) {
            unsigned x = __shfl_down(suf3, off, 64);
            if (lane + off < 16) suf3 += x;
        }
        u64 bal3 = __ballot((lane < 16) && (rest2 + suf3 >= TOPN));
        int bsel = 63 - __builtin_clzll(bal3);
        if (lane == 0) thr_sh = ((unsigned)(S * 16 + bsel)) << 18;
    }
    __syncthreads();
    unsigned thr = thr_sh;             // count(uhigh >= thr) >= TOPN by construction

    for (int r = 0; r < 36; ++r) {     // coalesced re-load, ballot compact
        unsigned u = uhigh[t + r * 1024];
        bool pred = (u >= thr);
        u64 b = __ballot(pred);
        int nb = __popcll(b);
        unsigned base = 0;
        if (lane == 0 && nb) base = atomicAdd(&cnt_sh, (unsigned)nb);
        base = __shfl(base, 0, 64);
        if (pred) {
            unsigned p = base + (unsigned)__popcll(b & ((1ULL << lane) - 1ULL));
            if (p < MAXSEL)
                sel[p] = ((u64)u << 32) |
                         (u64)(0xFFFFFFFFu - (unsigned)(t + r * 1024));
        }
    }
    __syncthreads();
    if (t == 0) *nsel = (cnt_sh > MAXSEL) ? MAXSEL : cnt_sh;
}

// ---------- fused rank + scatter: block b fully ranks candidates [32b,32b+32) ----------
__global__ __launch_bounds__(256) void rank_scatter(
        const u64* __restrict__ sel,
        const unsigned* __restrict__ nsel,
        const float* __restrict__ deltas,
        float4* __restrict__ topb,
        float* __restrict__ areas,
        unsigned* __restrict__ topu) {
    __shared__ u64 tile[1024];
    __shared__ int pr[256];            // 8 segments x 32 candidates
    int t = threadIdx.x;
    int slot = t & 31, seg = t >> 5;   // candidate slot, segment
    int n = (int)*nsel; if (n > MAXSEL) n = MAXSEL;
    int j = blockIdx.x * 32 + slot;
    u64 myk = (j < n) ? sel[j] : 0ULL;
    int rk = 0;
    for (int base = 0; base < n; base += 1024) {
        int m = min(1024, n - base);
        for (int q = t; q < m; q += 256) tile[q] = sel[base + q];
        __syncthreads();
        for (int q = seg; q < m; q += 8) rk += (tile[q] > myk) ? 1 : 0;
        __syncthreads();
    }
    pr[seg * 32 + slot] = rk;
    __syncthreads();
    if (t < 32) {
        int jj = blockIdx.x * 32 + t;
        int rtot = 0;
        #pragma unroll
        for (int s2 = 0; s2 < 8; ++s2) rtot += pr[s2 * 32 + t];
        if (jj < n && rtot < TOPN) {
            u64 k = sel[jj];
            unsigned idx = 0xFFFFFFFFu - (unsigned)(k & 0xFFFFFFFFull);
            bool valid;
            float4 b = decode_box(deltas, (int)idx, &valid);
            topb[rtot]  = b;
            areas[rtot] = box_area(b);
            topu[rtot]  = (unsigned)(k >> 32);
        }
    }
}

// ---------- grid-parallel IoU suppression bit matrix (j > i only) ----------
__global__ void nms_mask(const float4* __restrict__ boxes,
                         const float* __restrict__ areas,
                         u64* __restrict__ mask) {
    int rb = blockIdx.x, cb = blockIdx.y;
    if (cb < rb) return;                       // sub-diagonal words never read
    __shared__ float4 cbx[64];
    __shared__ float  car[64];
    int tid = threadIdx.x;
    int j0 = cb * 64;
    if (j0 + tid < TOPN) { cbx[tid] = boxes[j0 + tid]; car[tid] = areas[j0 + tid]; }
    __syncthreads();
    int i = rb * 64 + tid;
    if (i >= TOPN) return;
    float4 bi = boxes[i];
    float  ai = areas[i];
    u64 bits = 0ULL;
    int jmax = min(64, TOPN - j0);
    for (int jj = 0; jj < jmax; ++jj) {
        int j = j0 + jj;
        if (j <= i) continue;
        float4 bj = cbx[jj];
        float xx1 = fmaxf(bi.x, bj.x);
        float yy1 = fmaxf(bi.y, bj.y);
        float xx2 = fminf(bi.z, bj.z);
        float yy2 = fminf(bi.w, bj.w);
        float w = fmaxf(__fadd_rn(__fsub_rn(xx2, xx1), 1.0f), 0.0f);
        float h = fmaxf(__fadd_rn(__fsub_rn(yy2, yy1), 1.0f), 0.0f);
        float inter = __fmul_rn(w, h);
        float denom = __fsub_rn(__fadd_rn(ai, car[jj]), inter);
        float iou = inter / denom;              // IEEE-exact, matches numpy
        if (iou > 0.5f) bits |= (1ULL << jj);
    }
    mask[(size_t)i * NWORDS + cb] = bits;
}

// ---------- greedy scan: zero dependent global loads on the critical path ----------
// 1024 thr. Per 128-row round r: wave0 resolves from the prefetched 4-word
// diagonal tile (words 2r..2r+3), computes the URGENT suppression for the next
// round's words from tile words [2],[3] via an in-wave shfl-OR reduce (kept in
// registers), and does lane-parallel bookkeeping. Concurrently waves 1-14
// LAZY-apply round r-1's kept rows to words >= 2r+2, and wave 15 prefetches
// round r+1's diagonal tile + finite flags. -inf boxes suppress but are
// excluded from output (ref applies isfinite AFTER nms).
__global__ __launch_bounds__(1024) void nms_scan(
        const u64* __restrict__ mask,
        const unsigned* __restrict__ topu,
        const float4* __restrict__ topb,
        float* __restrict__ out) {
    __shared__ unsigned rem32[NWORDS * 2];
    __shared__ u64 diag[2][128][4];     // 8 KB
    __shared__ u64 Fsh[2][2];
    __shared__ short kept_rows[2][128];
    __shared__ short kept_list[POSTN];
    __shared__ int nk_sh[2];
    __shared__ int cnt_sh, stop_sh;

    int t = threadIdx.x, wave = t >> 6, lane = t & 63;
    if (t >= 640 && t < 640 + NWORDS * 2) rem32[t - 640] = 0;
    if (t >= 128 && t < 640) {          // round-0 tile: rows 0..127, words 0..3
        int idx = t - 128;
        diag[0][idx >> 2][idx & 3] = mask[(size_t)(idx >> 2) * NWORDS + (idx & 3)];
    }
    if (wave == 0) {
        u64 f = __ballot(topu[lane] != NEGINF_PAT);
        if (lane == 0) { Fsh[0][0] = f; cnt_sh = 0; stop_sh = 0; nk_sh[0] = 0; nk_sh[1] = 0; }
    } else if (wave == 1) {
        u64 f = __ballot(topu[64 + lane] != NEGINF_PAT);
        if (lane == 0) Fsh[0][1] = f;
    }
    __syncthreads();

    u64 urg0 = 0, urg1 = 0;   // wave0: urgent removed-bits for next round's 2 words

    for (int r = 0; r < NROUND; ++r) {
        int p = r & 1;
        int i0 = r * 128;
        if (wave == 0) {
            u64 r0w0 = diag[p][lane][0];
            u64 r0w1 = diag[p][lane][1];
            u64 r1w1 = diag[p][64 + lane][1];
            u64 R0 = ((u64)rem32[4 * r]     | ((u64)rem32[4 * r + 1] << 32)) | urg0;
            u64 R1 = ((u64)rem32[4 * r + 2] | ((u64)rem32[4 * r + 3] << 32)) | urg1;
            int nb = min(128, TOPN - i0);           // 128, or 112 on last round
            u64 v1 = (nb >= 128) ? ~0ULL : ((1ULL << (nb - 64)) - 1ULL);
            u64 a0 = ~R0;
            u64 a1 = ~R1 & v1;
            u64 k0 = 0ULL, k1 = 0ULL;
            while (a0) {
                int ii = __builtin_ctzll(a0);
                u64 bit = 1ULL << ii;
                k0 |= bit;
                u64 s0 = __shfl(r0w0, ii, 64);
                u64 s1 = __shfl(r0w1, ii, 64);
                a0 &= ~(s0 | bit);
                a1 &= ~s1;
            }
            while (a1) {
                int ii = __builtin_ctzll(a1);
                u64 bit = 1ULL << ii;
                k1 |= bit;
                u64 s1 = __shfl(r1w1, ii, 64);
                a1 &= ~(s1 | bit);
            }
            // lane-parallel bookkeeping
            u64 F0 = Fsh[p][0], F1 = Fsh[p][1];
            u64 kf0 = k0 & F0, kf1 = k1 & F1;
            int nk0 = __popcll(k0);
            int c0  = __popcll(kf0);
            int base = cnt_sh;
            u64 ltm = (1ULL << lane) - 1ULL;        // bits strictly below lane
            if ((k0 >> lane) & 1)
                kept_rows[p][__popcll(k0 & ltm)] = (short)(i0 + lane);
            if ((k1 >> lane) & 1)
                kept_rows[p][nk0 + __popcll(k1 & ltm)] = (short)(i0 + 64 + lane);
            if ((kf0 >> lane) & 1) {
                int pos = base + __popcll(kf0 & ltm);
                if (pos < POSTN) kept_list[pos] = (short)(i0 + lane);
            }
            if ((kf1 >> lane) & 1) {
                int pos = base + c0 + __popcll(kf1 & ltm);
                if (pos < POSTN) kept_list[pos] = (short)(i0 + 64 + lane);
            }
            // urgent for next round (words 2r+2..3) from tile words [2],[3]
            u64 a0u = 0ULL, a1u = 0ULL;
            if ((k0 >> lane) & 1) { a0u = diag[p][lane][2];       a1u = diag[p][lane][3]; }
            if ((k1 >> lane) & 1) { a0u |= diag[p][64 + lane][2]; a1u |= diag[p][64 + lane][3]; }
            #pragma unroll
            for (int off = 1; off < 64; off <<= 1) {
                a0u |= __shfl_xor(a0u, off, 64);
                a1u |= __shfl_xor(a1u, off, 64);
            }
            urg0 = a0u; urg1 = a1u;
            if (lane == 0) {
                nk_sh[p] = nk0 + __popcll(k1);
                int cc = base + c0 + __popcll(kf1);
                if (cc > POSTN) cc = POSTN;
                cnt_sh = cc;
                stop_sh = (cc >= POSTN) || (r == NROUND - 1);
            }
        } else if (wave == 15) {
            if (r + 1 < NROUND) {       // prefetch round r+1 tile + finite flags
                int i1 = i0 + 128;
                #pragma unroll
                for (int q = lane; q < 512; q += 64) {
                    int row = i1 + (q >> 2), k = q & 3;
                    int wd = 2 * (r + 1) + k;
                    diag[p ^ 1][q >> 2][k] = (row < TOPN && wd < NWORDS)
                        ? mask[(size_t)row * NWORDS + wd] : 0ULL;
                }
                u64 fa = __ballot((i1 + lane < TOPN) && (topu[i1 + lane] != NEGINF_PAT));
                u64 fb = __ballot((i1 + 64 + lane < TOPN) && (topu[i1 + 64 + lane] != NEGINF_PAT));
                if (lane == 0) { Fsh[p ^ 1][0] = fa; Fsh[p ^ 1][1] = fb; }
            }
        } else {
            // lazy apply: round r-1's kept rows, words >= 2r+2 (read at round r+1)
            int nkp = nk_sh[p ^ 1];
            int left = NWORDS - (2 * r + 2);
            if (r > 0 && nkp > 0 && left > 0) {
                int tot = nkp * left;
                for (int q = t - 64; q < tot; q += 896) {
                    int k  = q / left;
                    int wd = 2 * r + 2 + (q - k * left);
                    int row = kept_rows[p ^ 1][k];
                    u64 v = mask[(size_t)row * NWORDS + wd];
                    if (v) {
                        unsigned lo = (unsigned)v, hi = (unsigned)(v >> 32);
                        if (lo) atomicOr(&rem32[2 * wd],     lo);
                        if (hi) atomicOr(&rem32[2 * wd + 1], hi);
                    }
                }
            }
        }
        __syncthreads();
        if (stop_sh) break;
    }

    // fused output: first 300 kept (rank order), /1024, zero-fill rest
    if (t < POSTN) {
        float4 v = make_float4(0.f, 0.f, 0.f, 0.f);
        if (t < cnt_sh) {
            float4 b = topb[kept_list[t]];
            const float s = 0.0009765625f;   // 1/1024 (exact)
            v = make_float4(b.x * s, b.y * s, b.z * s, b.w * s);
        }
        ((float4*)out)[t] = v;
    }
}

extern "C" void kernel_launch(void* const* d_in, const int* in_sizes, int n_in,
                              void* d_out, int out_size, void* d_ws, size_t ws_size,
                              hipStream_t stream) {
    const float* scores = (const float*)d_in[0];   // (1,64,64,18)
    const float* deltas = (const float*)d_in[1];   // (1,64,64,36)
    float* out = (float*)d_out;                    // 300*4

    char* w = (char*)d_ws;
    unsigned* uhigh = (unsigned*)(w);               //       0 ..  147456
    u64*      sel   = (u64*)(w + 147456);           //  147456 ..  212992
    unsigned* nsel  = (unsigned*)(w + 212992);      //  212992 ..  213008
    float4*   topb  = (float4*)(w + 213008);        //  213008 ..  309008
    float*    areas = (float*)(w + 309008);         //  309008 ..  333008
    unsigned* topu  = (unsigned*)(w + 333008);      //  333008 ..  357008
    u64*      mask  = (u64*)(w + 357008);           //  357008 .. 4869008 (4.5 MB)

    decode_kernel<<<NPROP / 256, 256, 0, stream>>>(scores, deltas, uhigh);
    select_compact<<<1, 1024, 0, stream>>>(uhigh, sel, nsel);
    rank_scatter<<<MAXSEL / 32, 256, 0, stream>>>(sel, nsel, deltas, topb, areas, topu);
    nms_mask<<<dim3(NWORDS, NWORDS), 64, 0, stream>>>(topb, areas, mask);
    nms_scan<<<1, 1024, 0, stream>>>(mask, topu, topb, out);
}

// Round 10
// 150.328 us; speedup vs baseline: 4.1284x; 1.1681x over previous
//
#include <hip/hip_runtime.h>
#include <math.h>

// Caffe-style RPN proposal layer on gfx950.
// scores (1,64,64,18) f32 + deltas (1,64,64,36) f32 -> (300,4) f32.
// Pipeline (6 dispatches):
//   decode (uhigh only)
//   -> select_compact (transposed LDS hist, wave-parallel descent, ballot compact)
//   -> rank_partial (8-way split exact ranking, atomic-free, unrolled)
//   -> scatter_top (sum partials + re-decode scatter)
//   -> nms_mask (grid IoU bit matrix) -> nms_scan (latency-hidden greedy, fused out)

#define NPROP   36864
#define TOPN    6000
#define POSTN   300
#define NWORDS  94          // ceil(6000/64)
#define NROUND  47          // ceil(6000/128)
#define MAXSEL  8192
#define NB      16384       // 14-bit histogram buckets
#define SPLIT   8
#define NEGINF_PAT 0x007FFFFFu   // sortable pattern of -inf score

typedef unsigned long long u64;

// classic 9 anchors for base=16, ratios {0.5,1,2}, scales {8,16,32}
__constant__ float ANCH[9][4] = {
    {-84.f,  -40.f,  99.f,  55.f},
    {-176.f, -88.f,  191.f, 103.f},
    {-360.f, -184.f, 375.f, 199.f},
    {-56.f,  -56.f,  71.f,  71.f},
    {-120.f, -120.f, 135.f, 135.f},
    {-248.f, -248.f, 263.f, 263.f},
    {-36.f,  -80.f,  51.f,  95.f},
    {-80.f,  -168.f, 95.f,  183.f},
    {-168.f, -344.f, 183.f, 359.f},
};

// decode box for anchor-index i (match unfused numpy rounding: no FMA)
__device__ __forceinline__ float4 decode_box(const float* __restrict__ deltas, int i,
                                             bool* valid_out) {
    int a   = i % 9;
    int pos = i / 9;
    int wx = pos & 63, hy = pos >> 6;
    float sx = (float)(wx * 16), sy = (float)(hy * 16);
    float ax1 = ANCH[a][0] + sx, ay1 = ANCH[a][1] + sy;
    float ax2 = ANCH[a][2] + sx, ay2 = ANCH[a][3] + sy;
    float aw  = ax2 - ax1 + 1.0f;
    float ah  = ay2 - ay1 + 1.0f;
    float acx = ax1 + 0.5f * aw;
    float acy = ay1 + 0.5f * ah;
    float4 d4 = ((const float4*)deltas)[i];   // (pos*36+a*4) floats == i*4 floats
    float pcx = __fadd_rn(__fmul_rn(d4.x, aw), acx);
    float pcy = __fadd_rn(__fmul_rn(d4.y, ah), acy);
    float pw  = __fmul_rn(expf(d4.z), aw);
    float ph  = __fmul_rn(expf(d4.w), ah);
    float hx  = __fmul_rn(0.5f, pw);
    float hv  = __fmul_rn(0.5f, ph);
    float x1 = fminf(fmaxf(__fsub_rn(pcx, hx), 0.0f), 1023.0f);
    float y1 = fminf(fmaxf(__fsub_rn(pcy, hv), 0.0f), 1023.0f);
    float x2 = fminf(fmaxf(__fadd_rn(pcx, hx), 0.0f), 1023.0f);
    float y2 = fminf(fmaxf(__fadd_rn(pcy, hv), 0.0f), 1023.0f);
    float bw = __fadd_rn(__fsub_rn(x2, x1), 1.0f);
    float bh = __fadd_rn(__fsub_rn(y2, y1), 1.0f);
    *valid_out = (bw >= 16.0f) && (bh >= 16.0f);
    return make_float4(x1, y1, x2, y2);
}

__device__ __forceinline__ float box_area(float4 b) {
    return __fmul_rn(__fadd_rn(__fsub_rn(b.z, b.x), 1.0f),
                     __fadd_rn(__fsub_rn(b.w, b.y), 1.0f));
}

// ---------- decode: sortable score word only ----------
__global__ __launch_bounds__(256) void decode_kernel(
        const float* __restrict__ scores,
        const float* __restrict__ deltas,
        unsigned* __restrict__ uhigh) {
    int i = blockIdx.x * 256 + threadIdx.x;   // exactly NPROP threads
    bool valid;
    (void)decode_box(deltas, i, &valid);
    int a = i % 9, pos = i / 9;
    float fg = scores[(size_t)pos * 18 + 9 + a];
    float sc = valid ? fg : -__builtin_huge_valf();
    unsigned u = __float_as_uint(sc);
    u = (u & 0x80000000u) ? ~u : (u | 0x80000000u);   // sortable: bigger = better
    uhigh[i] = u;
}

// ---------- single block: transposed LDS hist + wave-parallel descent + compact ----------
// Histogram transposed: bucket i at h[(i>>4) + (i&15)*1024], so strip sums
// (thread t owns buckets [16t,16t+16)) read stride-1024 = conflict-free.
// Threshold descent: 3-level (64/16/16) shfl suffix scan in wave 0.
__global__ __launch_bounds__(1024) void select_compact(
        const unsigned* __restrict__ uhigh,
        u64* __restrict__ sel,
        unsigned* __restrict__ nsel) {
    __shared__ unsigned h[NB];         // 64 KB, transposed
    __shared__ unsigned strip[1024];
    __shared__ unsigned thr_sh, cnt_sh;
    int t = threadIdx.x, lane = t & 63, wave = t >> 6;
    #pragma unroll
    for (int r = 0; r < NB / 1024; ++r) h[t + r * 1024] = 0;
    if (t == 0) cnt_sh = 0;
    __syncthreads();

    #pragma unroll
    for (int r = 0; r < 36; ++r) {     // NPROP/1024 == 36, coalesced
        unsigned u = uhigh[t + r * 1024];
        unsigned bkt = u >> 18;
        atomicAdd(&h[(bkt >> 4) + (bkt & 15) * 1024], 1u);
    }
    __syncthreads();

    unsigned s = 0;
    #pragma unroll
    for (int k = 0; k < 16; ++k) s += h[t + k * 1024];   // conflict-free
    strip[t] = s;
    __syncthreads();

    if (wave == 0) {
        // level 1: 64 group sums (16 strips each), suffix scan, pick group
        unsigned g = 0;
        #pragma unroll
        for (int k = 0; k < 16; ++k) g += strip[lane * 16 + k];
        unsigned suf = g;
        #pragma unroll
        for (int off = 1; off < 64; off <<= 1) {
            unsigned x = __shfl_down(suf, off, 64);
            if (lane + off < 64) suf += x;
        }
        u64 bal = __ballot(suf >= TOPN);
        int gsel = 63 - __builtin_clzll(bal);
        unsigned rest = __shfl(suf, (gsel < 63) ? gsel + 1 : 63, 64);
        if (gsel == 63) rest = 0;

        // level 2: 16 strips within group gsel
        unsigned sv = (lane < 16) ? strip[gsel * 16 + lane] : 0;
        unsigned suf2 = sv;
        #pragma unroll
        for (int off = 1; off < 16; off <<= 1) {
            unsigned x = __shfl_down(suf2, off, 64);
            if (lane + off < 16) suf2 += x;
        }
        u64 bal2 = __ballot((lane < 16) && (rest + suf2 >= TOPN));
        int ssel = 63 - __builtin_clzll(bal2);
        unsigned rest2 = __shfl(suf2, (ssel < 15) ? ssel + 1 : 15, 64);
        if (ssel == 15) rest2 = 0;
        rest2 += rest;
        int S = gsel * 16 + ssel;      // strip index 0..1023

        // level 3: 16 buckets within strip S; bucket S*16+lane at h[S+lane*1024]
        unsigned bv = (lane < 16) ? h[S + lane * 1024] : 0;
        unsigned suf3 = bv;
        #pragma unroll
        for (int off = 1; off < 16; off <<= 1) {
            unsigned x = __shfl_down(suf3, off, 64);
            if (lane + off < 16) suf3 += x;
        }
        u64 bal3 = __ballot((lane < 16) && (rest2 + suf3 >= TOPN));
        int bsel = 63 - __builtin_clzll(bal3);
        if (lane == 0) thr_sh = ((unsigned)(S * 16 + bsel)) << 18;
    }
    __syncthreads();
    unsigned thr = thr_sh;             // count(uhigh >= thr) >= TOPN by construction

    for (int r = 0; r < 36; ++r) {     // coalesced re-load, ballot compact
        unsigned u = uhigh[t + r * 1024];
        bool pred = (u >= thr);
        u64 b = __ballot(pred);
        int nb = __popcll(b);
        unsigned base = 0;
        if (lane == 0 && nb) base = atomicAdd(&cnt_sh, (unsigned)nb);
        base = __shfl(base, 0, 64);
        if (pred) {
            unsigned p = base + (unsigned)__popcll(b & ((1ULL << lane) - 1ULL));
            if (p < MAXSEL)
                sel[p] = ((u64)u << 32) |
                         (u64)(0xFFFFFFFFu - (unsigned)(t + r * 1024));
        }
    }
    __syncthreads();
    if (t == 0) *nsel = (cnt_sh > MAXSEL) ? MAXSEL : cnt_sh;
}

// ---------- exact rank by counting, inner dim split SPLIT ways, atomic-free ----------
__global__ __launch_bounds__(256) void rank_partial(
        const u64* __restrict__ sel,
        const unsigned* __restrict__ nsel,
        int* __restrict__ rank8) {
    __shared__ u64 tile[1024];
    int t = threadIdx.x;
    int j = blockIdx.x * 256 + t;
    int n = (int)*nsel;
    int T = (n + SPLIT - 1) / SPLIT;
    int lo = blockIdx.y * T;
    int hi = min(lo + T, n);
    u64 myk = (j < n) ? sel[j] : 0ULL;
    int rk = 0;
    for (int base = lo; base < hi; base += 1024) {
        int m = min(1024, hi - base);
        for (int q = t; q < m; q += 256) tile[q] = sel[base + q];
        __syncthreads();
        #pragma unroll 4
        for (int q = 0; q < m; ++q) rk += (tile[q] > myk) ? 1 : 0;
        __syncthreads();
    }
    rank8[blockIdx.y * MAXSEL + j] = rk;
}

// ---------- scatter to rank position, re-decoding the box ----------
__global__ __launch_bounds__(256) void scatter_top(
        const u64* __restrict__ sel,
        const unsigned* __restrict__ nsel,
        const int* __restrict__ rank8,
        const float* __restrict__ deltas,
        float4* __restrict__ topb,
        float* __restrict__ areas,
        unsigned* __restrict__ topu) {
    int j = blockIdx.x * 256 + threadIdx.x;
    int n = (int)*nsel;
    if (j >= n) return;
    int r = 0;
    #pragma unroll
    for (int s = 0; s < SPLIT; ++s) r += rank8[s * MAXSEL + j];
    if (r >= TOPN) return;
    u64 k = sel[j];
    unsigned idx = 0xFFFFFFFFu - (unsigned)(k & 0xFFFFFFFFull);
    bool valid;
    float4 b = decode_box(deltas, (int)idx, &valid);
    topb[r]  = b;
    areas[r] = box_area(b);
    topu[r]  = (unsigned)(k >> 32);
}

// ---------- grid-parallel IoU suppression bit matrix (j > i only) ----------
__global__ void nms_mask(const float4* __restrict__ boxes,
                         const float* __restrict__ areas,
                         u64* __restrict__ mask) {
    int rb = blockIdx.x, cb = blockIdx.y;
    if (cb < rb) return;                       // sub-diagonal words never read
    __shared__ float4 cbx[64];
    __shared__ float  car[64];
    int tid = threadIdx.x;
    int j0 = cb * 64;
    if (j0 + tid < TOPN) { cbx[tid] = boxes[j0 + tid]; car[tid] = areas[j0 + tid]; }
    __syncthreads();
    int i = rb * 64 + tid;
    if (i >= TOPN) return;
    float4 bi = boxes[i];
    float  ai = areas[i];
    u64 bits = 0ULL;
    int jmax = min(64, TOPN - j0);
    for (int jj = 0; jj < jmax; ++jj) {
        int j = j0 + jj;
        if (j <= i) continue;
        float4 bj = cbx[jj];
        float xx1 = fmaxf(bi.x, bj.x);
        float yy1 = fmaxf(bi.y, bj.y);
        float xx2 = fminf(bi.z, bj.z);
        float yy2 = fminf(bi.w, bj.w);
        float w = fmaxf(__fadd_rn(__fsub_rn(xx2, xx1), 1.0f), 0.0f);
        float h = fmaxf(__fadd_rn(__fsub_rn(yy2, yy1), 1.0f), 0.0f);
        float inter = __fmul_rn(w, h);
        float denom = __fsub_rn(__fadd_rn(ai, car[jj]), inter);
        float iou = inter / denom;              // IEEE-exact, matches numpy
        if (iou > 0.5f) bits |= (1ULL << jj);
    }
    mask[(size_t)i * NWORDS + cb] = bits;
}

// ---------- greedy scan: zero dependent global loads on the critical path ----------
// 1024 thr. Per 128-row round r: wave0 resolves from the prefetched 4-word
// diagonal tile (words 2r..2r+3), computes the URGENT suppression for the next
// round's words from tile words [2],[3] via an in-wave shfl-OR reduce (kept in
// registers), and does lane-parallel bookkeeping. Concurrently waves 1-14
// LAZY-apply round r-1's kept rows to words >= 2r+2, and wave 15 prefetches
// round r+1's diagonal tile + finite flags. -inf boxes suppress but are
// excluded from output (ref applies isfinite AFTER nms).
__global__ __launch_bounds__(1024) void nms_scan(
        const u64* __restrict__ mask,
        const unsigned* __restrict__ topu,
        const float4* __restrict__ topb,
        float* __restrict__ out) {
    __shared__ unsigned rem32[NWORDS * 2];
    __shared__ u64 diag[2][128][4];     // 8 KB
    __shared__ u64 Fsh[2][2];
    __shared__ short kept_rows[2][128];
    __shared__ short kept_list[POSTN];
    __shared__ int nk_sh[2];
    __shared__ int cnt_sh, stop_sh;

    int t = threadIdx.x, wave = t >> 6, lane = t & 63;
    if (t >= 640 && t < 640 + NWORDS * 2) rem32[t - 640] = 0;
    if (t >= 128 && t < 640) {          // round-0 tile: rows 0..127, words 0..3
        int idx = t - 128;
        diag[0][idx >> 2][idx & 3] = mask[(size_t)(idx >> 2) * NWORDS + (idx & 3)];
    }
    if (wave == 0) {
        u64 f = __ballot(topu[lane] != NEGINF_PAT);
        if (lane == 0) { Fsh[0][0] = f; cnt_sh = 0; stop_sh = 0; nk_sh[0] = 0; nk_sh[1] = 0; }
    } else if (wave == 1) {
        u64 f = __ballot(topu[64 + lane] != NEGINF_PAT);
        if (lane == 0) Fsh[0][1] = f;
    }
    __syncthreads();

    u64 urg0 = 0, urg1 = 0;   // wave0: urgent removed-bits for next round's 2 words

    for (int r = 0; r < NROUND; ++r) {
        int p = r & 1;
        int i0 = r * 128;
        if (wave == 0) {
            u64 r0w0 = diag[p][lane][0];
            u64 r0w1 = diag[p][lane][1];
            u64 r1w1 = diag[p][64 + lane][1];
            u64 R0 = ((u64)rem32[4 * r]     | ((u64)rem32[4 * r + 1] << 32)) | urg0;
            u64 R1 = ((u64)rem32[4 * r + 2] | ((u64)rem32[4 * r + 3] << 32)) | urg1;
            int nb = min(128, TOPN - i0);           // 128, or 112 on last round
            u64 v1 = (nb >= 128) ? ~0ULL : ((1ULL << (nb - 64)) - 1ULL);
            u64 a0 = ~R0;
            u64 a1 = ~R1 & v1;
            u64 k0 = 0ULL, k1 = 0ULL;
            while (a0) {
                int ii = __builtin_ctzll(a0);
                u64 bit = 1ULL << ii;
                k0 |= bit;
                u64 s0 = __shfl(r0w0, ii, 64);
                u64 s1 = __shfl(r0w1, ii, 64);
                a0 &= ~(s0 | bit);
                a1 &= ~s1;
            }
            while (a1) {
                int ii = __builtin_ctzll(a1);
                u64 bit = 1ULL << ii;
                k1 |= bit;
                u64 s1 = __shfl(r1w1, ii, 64);
                a1 &= ~(s1 | bit);
            }
            // lane-parallel bookkeeping
            u64 F0 = Fsh[p][0], F1 = Fsh[p][1];
            u64 kf0 = k0 & F0, kf1 = k1 & F1;
            int nk0 = __popcll(k0);
            int c0  = __popcll(kf0);
            int base = cnt_sh;
            u64 ltm = (1ULL << lane) - 1ULL;        // bits strictly below lane
            if ((k0 >> lane) & 1)
                kept_rows[p][__popcll(k0 & ltm)] = (short)(i0 + lane);
            if ((k1 >> lane) & 1)
                kept_rows[p][nk0 + __popcll(k1 & ltm)] = (short)(i0 + 64 + lane);
            if ((kf0 >> lane) & 1) {
                int pos = base + __popcll(kf0 & ltm);
                if (pos < POSTN) kept_list[pos] = (short)(i0 + lane);
            }
            if ((kf1 >> lane) & 1) {
                int pos = base + c0 + __popcll(kf1 & ltm);
                if (pos < POSTN) kept_list[pos] = (short)(i0 + 64 + lane);
            }
            // urgent for next round (words 2r+2..3) from tile words [2],[3]
            u64 a0u = 0ULL, a1u = 0ULL;
            if ((k0 >> lane) & 1) { a0u = diag[p][lane][2];       a1u = diag[p][lane][3]; }
            if ((k1 >> lane) & 1) { a0u |= diag[p][64 + lane][2]; a1u |= diag[p][64 + lane][3]; }
            #pragma unroll
            for (int off = 1; off < 64; off <<= 1) {
                a0u |= __shfl_xor(a0u, off, 64);
                a1u |= __shfl_xor(a1u, off, 64);
            }
            urg0 = a0u; urg1 = a1u;
            if (lane == 0) {
                nk_sh[p] = nk0 + __popcll(k1);
                int cc = base + c0 + __popcll(kf1);
                if (cc > POSTN) cc = POSTN;
                cnt_sh = cc;
                stop_sh = (cc >= POSTN) || (r == NROUND - 1);
            }
        } else if (wave == 15) {
            if (r + 1 < NROUND) {       // prefetch round r+1 tile + finite flags
                int i1 = i0 + 128;
                #pragma unroll
                for (int q = lane; q < 512; q += 64) {
                    int row = i1 + (q >> 2), k = q & 3;
                    int wd = 2 * (r + 1) + k;
                    diag[p ^ 1][q >> 2][k] = (row < TOPN && wd < NWORDS)
                        ? mask[(size_t)row * NWORDS + wd] : 0ULL;
                }
                u64 fa = __ballot((i1 + lane < TOPN) && (topu[i1 + lane] != NEGINF_PAT));
                u64 fb = __ballot((i1 + 64 + lane < TOPN) && (topu[i1 + 64 + lane] != NEGINF_PAT));
                if (lane == 0) { Fsh[p ^ 1][0] = fa; Fsh[p ^ 1][1] = fb; }
            }
        } else {
            // lazy apply: round r-1's kept rows, words >= 2r+2 (read at round r+1)
            int nkp = nk_sh[p ^ 1];
            int left = NWORDS - (2 * r + 2);
            if (r > 0 && nkp > 0 && left > 0) {
                int tot = nkp * left;
                for (int q = t - 64; q < tot; q += 896) {
                    int k  = q / left;
                    int wd = 2 * r + 2 + (q - k * left);
                    int row = kept_rows[p ^ 1][k];
                    u64 v = mask[(size_t)row * NWORDS + wd];
                    if (v) {
                        unsigned lo = (unsigned)v, hi = (unsigned)(v >> 32);
                        if (lo) atomicOr(&rem32[2 * wd],     lo);
                        if (hi) atomicOr(&rem32[2 * wd + 1], hi);
                    }
                }
            }
        }
        __syncthreads();
        if (stop_sh) break;
    }

    // fused output: first 300 kept (rank order), /1024, zero-fill rest
    if (t < POSTN) {
        float4 v = make_float4(0.f, 0.f, 0.f, 0.f);
        if (t < cnt_sh) {
            float4 b = topb[kept_list[t]];
            const float s = 0.0009765625f;   // 1/1024 (exact)
            v = make_float4(b.x * s, b.y * s, b.z * s, b.w * s);
        }
        ((float4*)out)[t] = v;
    }
}

extern "C" void kernel_launch(void* const* d_in, const int* in_sizes, int n_in,
                              void* d_out, int out_size, void* d_ws, size_t ws_size,
                              hipStream_t stream) {
    const float* scores = (const float*)d_in[0];   // (1,64,64,18)
    const float* deltas = (const float*)d_in[1];   // (1,64,64,36)
    float* out = (float*)d_out;                    // 300*4

    char* w = (char*)d_ws;
    unsigned* uhigh = (unsigned*)(w);               //       0 ..  147456
    u64*      sel   = (u64*)(w + 147456);           //  147456 ..  212992
    unsigned* nsel  = (unsigned*)(w + 212992);      //  212992 ..  213008
    int*      rank8 = (int*)(w + 213008);           //  213008 ..  475152
    float4*   topb  = (float4*)(w + 475152);        //  475152 ..  571152
    float*    areas = (float*)(w + 571152);         //  571152 ..  595152
    unsigned* topu  = (unsigned*)(w + 595152);      //  595152 ..  619152
    u64*      mask  = (u64*)(w + 619152);           //  619152 .. 5131152 (4.5 MB)

    decode_kernel<<<NPROP / 256, 256, 0, stream>>>(scores, deltas, uhigh);
    select_compact<<<1, 1024, 0, stream>>>(uhigh, sel, nsel);
    rank_partial<<<dim3(MAXSEL / 256, SPLIT), 256, 0, stream>>>(sel, nsel, rank8);
    scatter_top<<<MAXSEL / 256, 256, 0, stream>>>(sel, nsel, rank8, deltas, topb, areas, topu);
    nms_mask<<<dim3(NWORDS, NWORDS), 64, 0, stream>>>(topb, areas, mask);
    nms_scan<<<1, 1024, 0, stream>>>(mask, topu, topb, out);
}